// Round 8
// baseline (185.994 us; speedup 1.0000x reference)
//
#include <hip/hip_runtime.h>
#include <hip/hip_cooperative_groups.h>

namespace cg = cooperative_groups;

#define H_    1024
#define B_    512
#define OUT_  512

typedef _Float16 half8 __attribute__((ext_vector_type(8)));
typedef _Float16 half4 __attribute__((ext_vector_type(4)));
typedef float    f32x4 __attribute__((ext_vector_type(4)));

__device__ __forceinline__ half8 cvt8(float4 lo, float4 hi) {
    half8 h;
    h[0] = (_Float16)lo.x; h[1] = (_Float16)lo.y; h[2] = (_Float16)lo.z; h[3] = (_Float16)lo.w;
    h[4] = (_Float16)hi.x; h[5] = (_Float16)hi.y; h[6] = (_Float16)hi.z; h[7] = (_Float16)hi.w;
    return h;
}

// Workgroup barrier WITHOUT the vmcnt(0) drain __syncthreads() emits.
__device__ __forceinline__ void barrier_nodrain() {
    asm volatile("s_waitcnt lgkmcnt(0)" ::: "memory");
    __builtin_amdgcn_s_barrier();
}

// ===========================================================================
// Phase 1: qkv partial GEMM. rawjob 0..767, decode (rawjob&7)*96+(rawjob>>3)
// is bm-fastest + XCD-chunked. 64x64 tile, BK=64, K-split x2, f16 partials.
// ===========================================================================
__device__ __forceinline__ void phase1_qkv(int rawjob, int tid,
                                           const float* __restrict__ x,
                                           const float* __restrict__ Wq,
                                           const float* __restrict__ Wk,
                                           const float* __restrict__ Wv,
                                           _Float16* __restrict__ qkvph,
                                           char* smem)
{
    _Float16* sA = (_Float16*)smem;            // [2][64*64]
    _Float16* sB = (_Float16*)(smem + 16384);  // [2][64*64]

    const int lane = tid & 63;
    const int w    = tid >> 6;
    const int wr   = w >> 1, wc = w & 1;
    const int fr   = lane & 15, fg = lane >> 4;

    const int job  = (rawjob & 7) * 96 + (rawjob >> 3);
    const int bm   = (job & 7) * 64;
    const int rest = job >> 3;                 // 0..95
    const int kz   = (rest >= 48) ? 1 : 0;
    const int bn   = (rest - kz * 48) * 64;    // 0..3071
    const int k0   = kz * 512;

    const int wsel = bn >> 10;
    const float* W = (wsel == 0) ? Wq : (wsel == 1) ? Wk : Wv;
    const int brow = bn & 1023;

    const int srow = tid >> 2;
    const int cq   = tid & 3;
    const float* Ap = x + (size_t)(bm + srow) * H_ + k0 + cq * 16;
    const float* Bp = W + (size_t)(brow + srow) * H_ + k0 + cq * 16;

    const int g0    = (((2 * cq)     ^ (srow & 7)) << 3);
    const int g1    = (((2 * cq + 1) ^ (srow & 7)) << 3);
    const int wbase = srow * 64;

    f32x4 acc[2][2] = {};

    float4 a0 = *(const float4*)(Ap + 0), a1 = *(const float4*)(Ap + 4);
    float4 a2 = *(const float4*)(Ap + 8), a3 = *(const float4*)(Ap + 12);
    float4 b0 = *(const float4*)(Bp + 0), b1 = *(const float4*)(Bp + 4);
    float4 b2 = *(const float4*)(Bp + 8), b3 = *(const float4*)(Bp + 12);

    for (int t = 0; t < 8; ++t) {
        const int buf = (t & 1) << 12;         // 0 / 4096 halves
        half8 hA0 = cvt8(a0, a1), hA1 = cvt8(a2, a3);
        half8 hB0 = cvt8(b0, b1), hB1 = cvt8(b2, b3);
        if (t < 7) {
            const float* An = Ap + (t + 1) * 64;
            const float* Bn = Bp + (t + 1) * 64;
            a0 = *(const float4*)(An + 0); a1 = *(const float4*)(An + 4);
            a2 = *(const float4*)(An + 8); a3 = *(const float4*)(An + 12);
            b0 = *(const float4*)(Bn + 0); b1 = *(const float4*)(Bn + 4);
            b2 = *(const float4*)(Bn + 8); b3 = *(const float4*)(Bn + 12);
        }
        *(half8*)&sA[buf + wbase + g0] = hA0;
        *(half8*)&sA[buf + wbase + g1] = hA1;
        *(half8*)&sB[buf + wbase + g0] = hB0;
        *(half8*)&sB[buf + wbase + g1] = hB1;
        barrier_nodrain();

#pragma unroll
        for (int kh = 0; kh < 2; ++kh) {
            const int p = (((kh * 4 + fg) ^ (fr & 7)) << 3);
            half8 af[2], bf[2];
#pragma unroll
            for (int mi = 0; mi < 2; ++mi)
                af[mi] = *(const half8*)&sA[buf + (wr * 32 + mi * 16 + fr) * 64 + p];
#pragma unroll
            for (int ni = 0; ni < 2; ++ni)
                bf[ni] = *(const half8*)&sB[buf + (wc * 32 + ni * 16 + fr) * 64 + p];
#pragma unroll
            for (int mi = 0; mi < 2; ++mi)
#pragma unroll
                for (int ni = 0; ni < 2; ++ni)
                    acc[mi][ni] = __builtin_amdgcn_mfma_f32_16x16x32_f16(
                                      af[mi], bf[ni], acc[mi][ni], 0, 0, 0);
        }
    }

    _Float16* Cb = qkvph + ((size_t)kz * B_ + bm) * 3072 + bn;
#pragma unroll
    for (int mi = 0; mi < 2; ++mi) {
        const int r0 = wr * 32 + mi * 16 + fg * 4;
#pragma unroll
        for (int ni = 0; ni < 2; ++ni) {
            const int col = wc * 32 + ni * 16 + fr;
#pragma unroll
            for (int r = 0; r < 4; ++r)
                Cb[(size_t)(r0 + r) * 3072 + col] = (_Float16)acc[mi][ni][r];
        }
    }
}

// ===========================================================================
// Phase 2: per-batch Taylor moments (deg 7) + Horner eval -> attnh f16.
// ===========================================================================
__device__ __forceinline__ void phase2_attn(int b, int tid,
                                            const _Float16* __restrict__ qkvph,
                                            const float* __restrict__ bv,
                                            _Float16* __restrict__ attnh,
                                            char* smem)
{
    float* red = (float*)smem;                 // [4][16]
    float* sm  = (float*)(smem + 256);         // [16]
    const _Float16* p0 = qkvph + (size_t)b * 3072;
    const _Float16* p1 = qkvph + (size_t)(B_ + b) * 3072;

    half4 ka = ((const half4*)(p0 + 1024))[tid];
    half4 kb = ((const half4*)(p1 + 1024))[tid];
    half4 va = ((const half4*)(p0 + 2048))[tid];
    half4 vb = ((const half4*)(p1 + 2048))[tid];
    float4 bv4 = ((const float4*)bv)[tid];

    const float ks[4] = {(float)ka[0] + (float)kb[0], (float)ka[1] + (float)kb[1],
                         (float)ka[2] + (float)kb[2], (float)ka[3] + (float)kb[3]};
    const float vs[4] = {(float)va[0] + (float)vb[0] + bv4.x,
                         (float)va[1] + (float)vb[1] + bv4.y,
                         (float)va[2] + (float)vb[2] + bv4.z,
                         (float)va[3] + (float)vb[3] + bv4.w};

    float m[8] = {}, Mv[8] = {};
#pragma unroll
    for (int e = 0; e < 4; ++e) {
        float s = ks[e] * (1.0f / 32.0f);
        float v = vs[e];
        float p = 1.0f;
#pragma unroll
        for (int n = 0; n < 8; ++n) {
            m[n] += p;
            Mv[n] = fmaf(p, v, Mv[n]);
            p *= s;
        }
    }
#pragma unroll
    for (int off = 32; off; off >>= 1)
#pragma unroll
        for (int n = 0; n < 8; ++n) {
            m[n]  += __shfl_xor(m[n],  off, 64);
            Mv[n] += __shfl_xor(Mv[n], off, 64);
        }
    const int wave = tid >> 6;
    if ((tid & 63) == 0) {
#pragma unroll
        for (int n = 0; n < 8; ++n) {
            red[wave * 16 + n]     = m[n];
            red[wave * 16 + n + 8] = Mv[n];
        }
    }
    __syncthreads();
    if (tid < 16) {
        const float invfact[8] = {1.f, 1.f, 0.5f, 1.f/6.f, 1.f/24.f,
                                  1.f/120.f, 1.f/720.f, 1.f/5040.f};
        sm[tid] = (red[tid] + red[16 + tid] + red[32 + tid] + red[48 + tid])
                  * invfact[tid & 7];
    }
    __syncthreads();

    half4 qa = ((const half4*)p0)[tid];
    half4 qb = ((const half4*)p1)[tid];
    half4 o;
#pragma unroll
    for (int e = 0; e < 4; ++e) {
        float c = (float)qa[e] + (float)qb[e];
        float den = sm[7];
#pragma unroll
        for (int n = 6; n >= 0; --n) den = fmaf(den, c, sm[n]);
        float num = sm[15];
#pragma unroll
        for (int n = 14; n >= 8; --n) num = fmaf(num, c, sm[n]);
        o[e] = (_Float16)(num / den);
    }
    ((half4*)attnh)[b * 256 + tid] = o;
}

// ===========================================================================
// Phase 3: out = attn @ Wo^T + bo. BM=BN=32, 256 jobs, chain 16 (BK=64).
// ===========================================================================
__device__ __forceinline__ void phase3_out(int d, int tid,
                                           const _Float16* __restrict__ attnh,
                                           const float* __restrict__ Wo,
                                           const float* __restrict__ bo,
                                           float* __restrict__ outp,
                                           char* smem)
{
    _Float16* sA = (_Float16*)smem;            // [2][32*64]
    _Float16* sB = (_Float16*)(smem + 8192);

    const int lane = tid & 63;
    const int w    = tid >> 6;
    const int wr   = w >> 1, wc = w & 1;
    const int fr   = lane & 15, fg = lane >> 4;

    const int job = (d & 7) * 32 + (d >> 3);   // 256 = 8*32, bijective
    const int bm  = (job & 15) * 32;
    const int bn  = (job >> 4) * 32;

    const int srow = tid >> 3;
    const int cg_  = tid & 7;
    const _Float16* Ap = attnh + (size_t)(bm + srow) * H_ + cg_ * 8;
    const float*    Bp = Wo    + (size_t)(bn + srow) * H_ + cg_ * 8;

    const int sw    = (cg_ ^ (srow & 7)) << 3;
    const int wbase = srow * 64;

    f32x4 acc = {};

    half8  a0 = *(const half8*)Ap;
    float4 b0 = *(const float4*)(Bp + 0), b1 = *(const float4*)(Bp + 4);

    for (int t = 0; t < 16; ++t) {
        const int buf = (t & 1) << 11;
        half8 hA = a0;
        half8 hB = cvt8(b0, b1);
        if (t < 15) {
            a0 = *(const half8*)(Ap + (t + 1) * 64);
            b0 = *(const float4*)(Bp + (t + 1) * 64);
            b1 = *(const float4*)(Bp + (t + 1) * 64 + 4);
        }
        *(half8*)&sA[buf + wbase + sw] = hA;
        *(half8*)&sB[buf + wbase + sw] = hB;
        barrier_nodrain();

#pragma unroll
        for (int kh = 0; kh < 2; ++kh) {
            const int p = (((kh * 4 + fg) ^ (fr & 7)) << 3);
            half8 af = *(const half8*)&sA[buf + (wr * 16 + fr) * 64 + p];
            half8 bf = *(const half8*)&sB[buf + (wc * 16 + fr) * 64 + p];
            acc = __builtin_amdgcn_mfma_f32_16x16x32_f16(af, bf, acc, 0, 0, 0);
        }
    }

    const int row0 = bm + wr * 16 + fg * 4;
    const int col  = bn + wc * 16 + fr;
    const float badd = bo[col];
#pragma unroll
    for (int r = 0; r < 4; ++r)
        outp[(size_t)(row0 + r) * OUT_ + col] = acc[r] + badd;
}

// ===========================================================================
// Cooperative fused kernel: 512 blocks x 256 thr, 2 blocks/CU (wide margin).
// Blocks < 256 run phase-1 jobs d and d+512 (persistent); same XCD chunks.
// ===========================================================================
__global__ void __launch_bounds__(256, 2)
fused_kernel(const float* __restrict__ x,  const float* __restrict__ Wq,
             const float* __restrict__ Wk, const float* __restrict__ Wv,
             const float* __restrict__ bv, const float* __restrict__ Wo,
             const float* __restrict__ bo, _Float16* __restrict__ qkvph,
             _Float16* __restrict__ attnh, float* __restrict__ outp)
{
    __shared__ __align__(16) char smem[32768];
    const int tid = threadIdx.x;
    const int d   = blockIdx.x;

    phase1_qkv(d, tid, x, Wq, Wk, Wv, qkvph, smem);
    if (d < 256) {
        __syncthreads();
        phase1_qkv(d + 512, tid, x, Wq, Wk, Wv, qkvph, smem);
    }

    cg::this_grid().sync();

    if (d < B_) phase2_attn(d, tid, qkvph, bv, attnh, smem);

    cg::this_grid().sync();

    if (d < 256) phase3_out(d, tid, attnh, Wo, bo, outp, smem);
}

// ===========================================================================
// Fallback path: 3 separate dispatches (identical phase code).
// ===========================================================================
__global__ __launch_bounds__(256) void qkv_kernel(const float* __restrict__ x,
                                                  const float* __restrict__ Wq,
                                                  const float* __restrict__ Wk,
                                                  const float* __restrict__ Wv,
                                                  _Float16* __restrict__ qkvph)
{
    __shared__ __align__(16) char smem[32768];
    phase1_qkv(blockIdx.x, threadIdx.x, x, Wq, Wk, Wv, qkvph, smem);
}

__global__ __launch_bounds__(256) void attn_kernel(const _Float16* __restrict__ qkvph,
                                                   const float* __restrict__ bv,
                                                   _Float16* __restrict__ attnh)
{
    __shared__ __align__(16) char smem[512];
    phase2_attn(blockIdx.x, threadIdx.x, qkvph, bv, attnh, smem);
}

__global__ __launch_bounds__(256) void out_kernel(const _Float16* __restrict__ attnh,
                                                  const float* __restrict__ Wo,
                                                  const float* __restrict__ bo,
                                                  float* __restrict__ outp)
{
    __shared__ __align__(16) char smem[16384];
    phase3_out(blockIdx.x, threadIdx.x, attnh, Wo, bo, outp, smem);
}

extern "C" void kernel_launch(void* const* d_in, const int* in_sizes, int n_in,
                              void* d_out, int out_size, void* d_ws, size_t ws_size,
                              hipStream_t stream)
{
    const float* x  = (const float*)d_in[0];
    const float* Wq = (const float*)d_in[1];
    const float* Wk = (const float*)d_in[2];
    const float* Wv = (const float*)d_in[3];
    const float* bv = (const float*)d_in[4];
    const float* Wo = (const float*)d_in[5];
    const float* bo = (const float*)d_in[6];
    float* out = (float*)d_out;

    char* ws = (char*)d_ws;
    _Float16* qkvph = (_Float16*)ws;                 // [2][512][3072] f16 = 6 MB
    _Float16* attnh = (_Float16*)(ws + (6 << 20));   // [512][1024] f16 = 1 MB

    // Host-side, capture-safe gating for the cooperative path.
    int coop = 0;
    if (hipDeviceGetAttribute(&coop, hipDeviceAttributeCooperativeLaunch, 0)
        != hipSuccess) coop = 0;
    if (coop) {
        int maxb = 0, ncu = 0;
        if (hipOccupancyMaxActiveBlocksPerMultiprocessor(
                &maxb, (const void*)fused_kernel, 256, 0) != hipSuccess) maxb = 0;
        if (hipDeviceGetAttribute(&ncu, hipDeviceAttributeMultiprocessorCount, 0)
            != hipSuccess) ncu = 0;
        if ((long)maxb * ncu < 512) coop = 0;
    }

    bool done = false;
    if (coop) {
        void* args[] = {(void*)&x, (void*)&Wq, (void*)&Wk, (void*)&Wv, (void*)&bv,
                        (void*)&Wo, (void*)&bo, (void*)&qkvph, (void*)&attnh,
                        (void*)&out};
        if (hipLaunchCooperativeKernel((const void*)fused_kernel, dim3(512),
                                       dim3(256), args, 0, stream) == hipSuccess)
            done = true;
    }
    if (!done) {
        qkv_kernel<<<dim3(768), 256, 0, stream>>>(x, Wq, Wk, Wv, qkvph);
        attn_kernel<<<dim3(B_), 256, 0, stream>>>(qkvph, bv, attnh);
        out_kernel<<<dim3(256), 256, 0, stream>>>(attnh, Wo, bo, out);
    }
}

// Round 9
// 42.228 us; speedup vs baseline: 4.4045x; 4.4045x over previous
//
#include <hip/hip_runtime.h>

#define H_    1024
#define B_    512
#define OUT_  512
#define SLAB_ ((size_t)B_ * 3072)

typedef _Float16 half8 __attribute__((ext_vector_type(8)));
typedef _Float16 half4 __attribute__((ext_vector_type(4)));
typedef float    f32x4 __attribute__((ext_vector_type(4)));

__device__ __forceinline__ half8 cvt8(float4 lo, float4 hi) {
    half8 h;
    h[0] = (_Float16)lo.x; h[1] = (_Float16)lo.y; h[2] = (_Float16)lo.z; h[3] = (_Float16)lo.w;
    h[4] = (_Float16)hi.x; h[5] = (_Float16)hi.y; h[6] = (_Float16)hi.z; h[7] = (_Float16)hi.w;
    return h;
}

// Workgroup barrier WITHOUT the vmcnt(0) drain __syncthreads() emits.
__device__ __forceinline__ void barrier_nodrain() {
    asm volatile("s_waitcnt lgkmcnt(0)" ::: "memory");
    __builtin_amdgcn_s_barrier();
}

// ===========================================================================
// qkv: A(x)-in-registers GEMM, K-split x8 (slab 128), f16 partials.
// 512 blocks x 512 thr. Block = 128 rows x 192 cols (3 x 64-col tiles) of one
// K-slab. kz = blockIdx&7 pins each slab to one XCD: per-XCD L2 working set
// = x-slab 256KB + W-slab 1.5MB (fully resident). LDS: W only, 2x8KB dbuf.
// 8 waves (4 wr x 2 wc), wave = 32x32, acc[2][2]; A-frags 32 VGPR, loaded
// once global->reg. Per step/thread: 1 ds_write + 4 ds_read (was 4+8).
// ===========================================================================
__global__ void __launch_bounds__(512, 4)
qkv_kernel(const float* __restrict__ x,  const float* __restrict__ Wq,
           const float* __restrict__ Wk, const float* __restrict__ Wv,
           _Float16* __restrict__ qkvph)
{
    __shared__ __align__(16) _Float16 sB[2][64 * 64];

    const int tid  = threadIdx.x;
    const int lane = tid & 63;
    const int w    = tid >> 6;        // 0..7
    const int wr   = w >> 1;          // 0..3 -> 32-row band
    const int wc   = w & 1;           // 0..1 -> 32-col band
    const int fr   = lane & 15, fg = lane >> 4;

    const int d   = blockIdx.x;
    const int kz  = d & 7;            // XCD-pinned K-slab
    const int inr = d >> 3;           // 0..63
    const int bm  = (inr & 3) * 128;
    const int grp = inr >> 2;         // 0..15 -> cols grp*192 .. +192
    const int k0  = kz * 128;

    // ---- A fragments: direct global->reg, whole 128-k slab (32 VGPR) ----
    half8 afr[2][4];
#pragma unroll
    for (int mi = 0; mi < 2; ++mi) {
        const float* ap = x + (size_t)(bm + wr * 32 + mi * 16 + fr) * H_ + k0 + fg * 8;
#pragma unroll
        for (int kc = 0; kc < 4; ++kc) {
            float4 lo = *(const float4*)(ap + kc * 32);
            float4 hi = *(const float4*)(ap + kc * 32 + 4);
            afr[mi][kc] = cvt8(lo, hi);
        }
    }

    // ---- B staging: thread covers (col srow, k-granule sg) ----
    const int srow = tid >> 3;        // 0..63
    const int sg   = tid & 7;         // 0..7
    const int swz  = srow * 64 + ((sg ^ (srow & 7)) << 3);

    auto wptr = [&](int s) -> const float* {   // s = 0..5 (bn-tile s>>1, half s&1)
        const int col  = grp * 192 + (s >> 1) * 64 + srow;   // 0..3071
        const int wsel = col >> 10;
        const float* W = (wsel == 0) ? Wq : (wsel == 1) ? Wk : Wv;
        return W + (size_t)(col & 1023) * H_ + k0 + (s & 1) * 64 + sg * 8;
    };

    f32x4 acc[2][2] = {};

    const float* bp = wptr(0);
    float4 b0 = *(const float4*)bp, b1 = *(const float4*)(bp + 4);

    for (int g6 = 0; g6 < 3; ++g6) {
#pragma unroll
        for (int t = 0; t < 2; ++t) {          // t compile-time: afr index static
            const int s   = g6 * 2 + t;
            const int buf = s & 1;
            half8 hB = cvt8(b0, b1);
            if (s < 5) {
                const float* np = wptr(s + 1);
                b0 = *(const float4*)np; b1 = *(const float4*)(np + 4);
            }
            *(half8*)&sB[buf][swz] = hB;
            barrier_nodrain();

#pragma unroll
            for (int kh = 0; kh < 2; ++kh) {
                const int p = (((kh * 4 + fg) ^ (fr & 7)) << 3);
                half8 bf[2];
#pragma unroll
                for (int ni = 0; ni < 2; ++ni)
                    bf[ni] = *(const half8*)&sB[buf][(wc * 32 + ni * 16 + fr) * 64 + p];
#pragma unroll
                for (int mi = 0; mi < 2; ++mi)
#pragma unroll
                    for (int ni = 0; ni < 2; ++ni)
                        acc[mi][ni] = __builtin_amdgcn_mfma_f32_16x16x32_f16(
                                          afr[mi][t * 2 + kh], bf[ni], acc[mi][ni], 0, 0, 0);
            }
        }

        // write this 64-col tile's partial (f16), reset acc
        const int bncol = grp * 192 + g6 * 64;
        _Float16* Cb = qkvph + (size_t)kz * SLAB_ + (size_t)bm * 3072 + bncol;
#pragma unroll
        for (int mi = 0; mi < 2; ++mi) {
            const int r0 = wr * 32 + mi * 16 + fg * 4;
#pragma unroll
            for (int ni = 0; ni < 2; ++ni) {
                const int col = wc * 32 + ni * 16 + fr;
#pragma unroll
                for (int r = 0; r < 4; ++r) {
                    Cb[(size_t)(r0 + r) * 3072 + col] = (_Float16)acc[mi][ni][r];
                    acc[mi][ni][r] = 0.0f;
                }
            }
        }
    }
}

// ===========================================================================
// attn: per-batch Taylor moments (deg 7) + Horner eval, summing 8 K-slab
// partials (+bv on v). Writes attnh f16.
// ===========================================================================
__global__ __launch_bounds__(256) void attn_kernel(const _Float16* __restrict__ qkvph,
                                                   const float* __restrict__ bv,
                                                   _Float16* __restrict__ attnh)
{
    __shared__ float red[4][16];
    __shared__ float sm[16];
    const int b   = blockIdx.x;
    const int tid = threadIdx.x;
    const _Float16* base = qkvph + (size_t)b * 3072;

    float ks[4] = {}, vs[4] = {}, qs[4] = {};
#pragma unroll
    for (int z = 0; z < 8; ++z) {
        const _Float16* pz = base + (size_t)z * SLAB_;
        half4 q4 = ((const half4*)(pz))[tid];
        half4 k4 = ((const half4*)(pz + 1024))[tid];
        half4 v4 = ((const half4*)(pz + 2048))[tid];
#pragma unroll
        for (int e = 0; e < 4; ++e) {
            qs[e] += (float)q4[e];
            ks[e] += (float)k4[e];
            vs[e] += (float)v4[e];
        }
    }
    float4 bv4 = ((const float4*)bv)[tid];
    vs[0] += bv4.x; vs[1] += bv4.y; vs[2] += bv4.z; vs[3] += bv4.w;

    float m[8] = {}, Mv[8] = {};
#pragma unroll
    for (int e = 0; e < 4; ++e) {
        float s = ks[e] * (1.0f / 32.0f);
        float v = vs[e];
        float p = 1.0f;
#pragma unroll
        for (int n = 0; n < 8; ++n) {
            m[n] += p;
            Mv[n] = fmaf(p, v, Mv[n]);
            p *= s;
        }
    }
#pragma unroll
    for (int off = 32; off; off >>= 1)
#pragma unroll
        for (int n = 0; n < 8; ++n) {
            m[n]  += __shfl_xor(m[n],  off, 64);
            Mv[n] += __shfl_xor(Mv[n], off, 64);
        }
    const int wave = tid >> 6;
    if ((tid & 63) == 0) {
#pragma unroll
        for (int n = 0; n < 8; ++n) {
            red[wave][n]     = m[n];
            red[wave][n + 8] = Mv[n];
        }
    }
    __syncthreads();
    if (tid < 16) {
        const float invfact[8] = {1.f, 1.f, 0.5f, 1.f/6.f, 1.f/24.f,
                                  1.f/120.f, 1.f/720.f, 1.f/5040.f};
        sm[tid] = (red[0][tid] + red[1][tid] + red[2][tid] + red[3][tid])
                  * invfact[tid & 7];
    }
    __syncthreads();

    half4 o;
#pragma unroll
    for (int e = 0; e < 4; ++e) {
        float c = qs[e];
        float den = sm[7];
#pragma unroll
        for (int n = 6; n >= 0; --n) den = fmaf(den, c, sm[n]);
        float num = sm[15];
#pragma unroll
        for (int n = 14; n >= 8; --n) num = fmaf(num, c, sm[n]);
        o[e] = (_Float16)(num / den);
    }
    ((half4*)attnh)[b * 256 + tid] = o;
}

// ===========================================================================
// out = attn @ Wo^T + bo. BM=BN=32, 256 blocks (XCD-chunked), BK=64, 16 steps.
// ===========================================================================
__global__ __launch_bounds__(256) void out_kernel(const _Float16* __restrict__ attnh,
                                                  const float* __restrict__ Wo,
                                                  const float* __restrict__ bo,
                                                  float* __restrict__ outp)
{
    __shared__ __align__(16) _Float16 sA[2][32 * 64];
    __shared__ __align__(16) _Float16 sB[2][32 * 64];

    const int tid  = threadIdx.x;
    const int lane = tid & 63;
    const int w    = tid >> 6;
    const int wr   = w >> 1, wc = w & 1;
    const int fr   = lane & 15, fg = lane >> 4;

    const int d   = blockIdx.x;
    const int job = (d & 7) * 32 + (d >> 3);   // 256 = 8*32, bijective
    const int bm  = (job & 15) * 32;
    const int bn  = (job >> 4) * 32;

    const int srow = tid >> 3;
    const int cg_  = tid & 7;
    const _Float16* Ap = attnh + (size_t)(bm + srow) * H_ + cg_ * 8;
    const float*    Bp = Wo    + (size_t)(bn + srow) * H_ + cg_ * 8;

    const int sw    = (cg_ ^ (srow & 7)) << 3;
    const int wbase = srow * 64;

    f32x4 acc = {};

    half8  a0 = *(const half8*)Ap;
    float4 b0 = *(const float4*)(Bp + 0), b1 = *(const float4*)(Bp + 4);

    for (int t = 0; t < 16; ++t) {
        const int buf = t & 1;
        half8 hA = a0;
        half8 hB = cvt8(b0, b1);
        if (t < 15) {
            a0 = *(const half8*)(Ap + (t + 1) * 64);
            b0 = *(const float4*)(Bp + (t + 1) * 64);
            b1 = *(const float4*)(Bp + (t + 1) * 64 + 4);
        }
        *(half8*)&sA[buf][wbase + sw] = hA;
        *(half8*)&sB[buf][wbase + sw] = hB;
        barrier_nodrain();

#pragma unroll
        for (int kh = 0; kh < 2; ++kh) {
            const int p = (((kh * 4 + fg) ^ (fr & 7)) << 3);
            half8 af = *(const half8*)&sA[buf][(wr * 16 + fr) * 64 + p];
            half8 bf = *(const half8*)&sB[buf][(wc * 16 + fr) * 64 + p];
            acc = __builtin_amdgcn_mfma_f32_16x16x32_f16(af, bf, acc, 0, 0, 0);
        }
    }

    const int row0 = bm + wr * 16 + fg * 4;
    const int col  = bn + wc * 16 + fr;
    const float badd = bo[col];
#pragma unroll
    for (int r = 0; r < 4; ++r)
        outp[(size_t)(row0 + r) * OUT_ + col] = acc[r] + badd;
}

extern "C" void kernel_launch(void* const* d_in, const int* in_sizes, int n_in,
                              void* d_out, int out_size, void* d_ws, size_t ws_size,
                              hipStream_t stream)
{
    const float* x  = (const float*)d_in[0];
    const float* Wq = (const float*)d_in[1];
    const float* Wk = (const float*)d_in[2];
    const float* Wv = (const float*)d_in[3];
    const float* bv = (const float*)d_in[4];
    const float* Wo = (const float*)d_in[5];
    const float* bo = (const float*)d_in[6];
    float* out = (float*)d_out;

    char* ws = (char*)d_ws;
    _Float16* qkvph = (_Float16*)ws;                  // [8][512][3072] f16 = 24 MB
    _Float16* attnh = (_Float16*)(ws + (24 << 20));   // [512][1024] f16 = 1 MB

    qkv_kernel<<<dim3(512), 512, 0, stream>>>(x, Wq, Wk, Wv, qkvph);
    attn_kernel<<<dim3(B_), 256, 0, stream>>>(qkvph, bv, attnh);
    out_kernel<<<dim3(256), 256, 0, stream>>>(attnh, Wo, bo, out);
}

// Round 10
// 39.087 us; speedup vs baseline: 4.7585x; 1.0804x over previous
//
#include <hip/hip_runtime.h>

#define H_    1024
#define B_    512
#define OUT_  512
#define SLAB_ ((size_t)B_ * 3072)

typedef _Float16 half8 __attribute__((ext_vector_type(8)));
typedef _Float16 half4 __attribute__((ext_vector_type(4)));
typedef float    f32x4 __attribute__((ext_vector_type(4)));

__device__ __forceinline__ half8 cvt8(float4 lo, float4 hi) {
    half8 h;
    h[0] = (_Float16)lo.x; h[1] = (_Float16)lo.y; h[2] = (_Float16)lo.z; h[3] = (_Float16)lo.w;
    h[4] = (_Float16)hi.x; h[5] = (_Float16)hi.y; h[6] = (_Float16)hi.z; h[7] = (_Float16)hi.w;
    return h;
}

// Workgroup barrier WITHOUT the vmcnt(0) drain __syncthreads() emits.
__device__ __forceinline__ void barrier_nodrain() {
    asm volatile("s_waitcnt lgkmcnt(0)" ::: "memory");
    __builtin_amdgcn_s_barrier();
}

// ===========================================================================
// qkv: 128x128 tile, 4 waves (2x2), wave = 64x64 (acc[4][4]), BK=64, 8 steps,
// K-split x2 -> f16 partials qkvph[kz][B][3072].
// Grid 192 = 8 XCD * 24: xcd owns {4 bm x 6 bn x 1 kz} (kz = xcd>>2) ->
// per-XCD L2 set = 1 MB x-half + 6*128-col W-half = 2.5 MB < 4 MB.
// LDS 64 KB dbuf; granule-XOR swizzle g' = g ^ (row&7) (proven R5-R6).
// Per wave-step: 8 ds_write + 16 ds_read vs 32 MFMA -> ratio 1.8:1 (R6: 3.6).
// ===========================================================================
__global__ void __launch_bounds__(256, 2)
qkv_kernel(const float* __restrict__ x,  const float* __restrict__ Wq,
           const float* __restrict__ Wk, const float* __restrict__ Wv,
           _Float16* __restrict__ qkvph)
{
    __shared__ __align__(16) _Float16 sA[2][128 * 64];
    __shared__ __align__(16) _Float16 sB[2][128 * 64];

    const int tid  = threadIdx.x;
    const int lane = tid & 63;
    const int w    = tid >> 6;
    const int wr   = w >> 1, wc = w & 1;       // wave = 64x64 quadrant
    const int fr   = lane & 15, fg = lane >> 4;

    const int d    = blockIdx.x;
    const int xcd  = d & 7;
    const int r    = d >> 3;                   // 0..23
    const int kz   = xcd >> 2;
    const int bn   = ((xcd & 3) * 6 + (r >> 2)) * 128;   // 0..2944
    const int bm   = (r & 3) * 128;
    const int k0   = kz * 512;

    const int wsel = bn >> 10;                 // tiles never straddle (1024%128==0)
    const float* W = (wsel == 0) ? Wq : (wsel == 1) ? Wk : Wv;
    const int brow = bn & 1023;

    // staging: thread covers row srow (0..127), granules 4cq..4cq+3 (32 halves)
    const int srow = tid >> 1;
    const int cq   = tid & 1;
    const float* Ap = x + (size_t)(bm + srow) * H_ + k0 + cq * 32;
    const float* Bp = W + (size_t)(brow + srow) * H_ + k0 + cq * 32;

    int goff[4];
#pragma unroll
    for (int j = 0; j < 4; ++j)
        goff[j] = srow * 64 + (((4 * cq + j) ^ (srow & 7)) << 3);

    f32x4 acc[4][4] = {};

    float4 a[8], b[8];
#pragma unroll
    for (int q = 0; q < 8; ++q) {
        a[q] = *(const float4*)(Ap + q * 4);
        b[q] = *(const float4*)(Bp + q * 4);
    }

    for (int t = 0; t < 8; ++t) {
        const int buf = t & 1;
        half8 hA[4], hB[4];
#pragma unroll
        for (int j = 0; j < 4; ++j) {
            hA[j] = cvt8(a[2 * j], a[2 * j + 1]);
            hB[j] = cvt8(b[2 * j], b[2 * j + 1]);
        }
        if (t < 7) {
            const float* An = Ap + (t + 1) * 64;
            const float* Bn = Bp + (t + 1) * 64;
#pragma unroll
            for (int q = 0; q < 8; ++q) {
                a[q] = *(const float4*)(An + q * 4);
                b[q] = *(const float4*)(Bn + q * 4);
            }
        }
#pragma unroll
        for (int j = 0; j < 4; ++j) {
            *(half8*)&sA[buf][goff[j]] = hA[j];
            *(half8*)&sB[buf][goff[j]] = hB[j];
        }
        barrier_nodrain();

#pragma unroll
        for (int kh = 0; kh < 2; ++kh) {
            const int p = (((kh * 4 + fg) ^ (fr & 7)) << 3);
            half8 af[4], bf[4];
#pragma unroll
            for (int mi = 0; mi < 4; ++mi)
                af[mi] = *(const half8*)&sA[buf][(wr * 64 + mi * 16 + fr) * 64 + p];
#pragma unroll
            for (int ni = 0; ni < 4; ++ni)
                bf[ni] = *(const half8*)&sB[buf][(wc * 64 + ni * 16 + fr) * 64 + p];
#pragma unroll
            for (int mi = 0; mi < 4; ++mi)
#pragma unroll
                for (int ni = 0; ni < 4; ++ni)
                    acc[mi][ni] = __builtin_amdgcn_mfma_f32_16x16x32_f16(
                                      af[mi], bf[ni], acc[mi][ni], 0, 0, 0);
        }
    }

    _Float16* Cb = qkvph + (size_t)kz * SLAB_ + (size_t)bm * 3072 + bn;
#pragma unroll
    for (int mi = 0; mi < 4; ++mi) {
        const int r0 = wr * 64 + mi * 16 + fg * 4;
#pragma unroll
        for (int ni = 0; ni < 4; ++ni) {
            const int col = wc * 64 + ni * 16 + fr;
#pragma unroll
            for (int rr = 0; rr < 4; ++rr)
                Cb[(size_t)(r0 + rr) * 3072 + col] = (_Float16)acc[mi][ni][rr];
        }
    }
}

// ===========================================================================
// attn: per-batch Taylor moments (deg 7) + Horner eval from 2 f16 K-partials
// (+bv on v). s_j = k/32, |c*s| <= ~0.85, remainder < 2e-5. Writes attnh f16.
// ===========================================================================
__global__ __launch_bounds__(256) void attn_kernel(const _Float16* __restrict__ qkvph,
                                                   const float* __restrict__ bv,
                                                   _Float16* __restrict__ attnh)
{
    __shared__ float red[4][16];
    __shared__ float sm[16];
    const int b   = blockIdx.x;
    const int tid = threadIdx.x;
    const _Float16* p0 = qkvph + (size_t)b * 3072;
    const _Float16* p1 = p0 + SLAB_;

    half4 ka = ((const half4*)(p0 + 1024))[tid];
    half4 kb = ((const half4*)(p1 + 1024))[tid];
    half4 va = ((const half4*)(p0 + 2048))[tid];
    half4 vb = ((const half4*)(p1 + 2048))[tid];
    float4 bv4 = ((const float4*)bv)[tid];

    const float ks[4] = {(float)ka[0] + (float)kb[0], (float)ka[1] + (float)kb[1],
                         (float)ka[2] + (float)kb[2], (float)ka[3] + (float)kb[3]};
    const float vs[4] = {(float)va[0] + (float)vb[0] + bv4.x,
                         (float)va[1] + (float)vb[1] + bv4.y,
                         (float)va[2] + (float)vb[2] + bv4.z,
                         (float)va[3] + (float)vb[3] + bv4.w};

    float m[8] = {}, Mv[8] = {};
#pragma unroll
    for (int e = 0; e < 4; ++e) {
        float s = ks[e] * (1.0f / 32.0f);
        float v = vs[e];
        float p = 1.0f;
#pragma unroll
        for (int n = 0; n < 8; ++n) {
            m[n] += p;
            Mv[n] = fmaf(p, v, Mv[n]);
            p *= s;
        }
    }
#pragma unroll
    for (int off = 32; off; off >>= 1)
#pragma unroll
        for (int n = 0; n < 8; ++n) {
            m[n]  += __shfl_xor(m[n],  off, 64);
            Mv[n] += __shfl_xor(Mv[n], off, 64);
        }
    const int wave = tid >> 6;
    if ((tid & 63) == 0) {
#pragma unroll
        for (int n = 0; n < 8; ++n) {
            red[wave][n]     = m[n];
            red[wave][n + 8] = Mv[n];
        }
    }
    __syncthreads();
    if (tid < 16) {
        const float invfact[8] = {1.f, 1.f, 0.5f, 1.f/6.f, 1.f/24.f,
                                  1.f/120.f, 1.f/720.f, 1.f/5040.f};
        sm[tid] = (red[0][tid] + red[1][tid] + red[2][tid] + red[3][tid])
                  * invfact[tid & 7];
    }
    __syncthreads();

    half4 qa = ((const half4*)p0)[tid];
    half4 qb = ((const half4*)p1)[tid];
    half4 o;
#pragma unroll
    for (int e = 0; e < 4; ++e) {
        float c = (float)qa[e] + (float)qb[e];
        float den = sm[7];
#pragma unroll
        for (int n = 6; n >= 0; --n) den = fmaf(den, c, sm[n]);
        float num = sm[15];
#pragma unroll
        for (int n = 14; n >= 8; --n) num = fmaf(num, c, sm[n]);
        o[e] = (_Float16)(num / den);
    }
    ((half4*)attnh)[b * 256 + tid] = o;
}

// ===========================================================================
// out = attn @ Wo^T + bo. BM=BN=32, 256 blocks (XCD-chunked), BK=64, 16 steps.
// ===========================================================================
__global__ __launch_bounds__(256) void out_kernel(const _Float16* __restrict__ attnh,
                                                  const float* __restrict__ Wo,
                                                  const float* __restrict__ bo,
                                                  float* __restrict__ outp)
{
    __shared__ __align__(16) _Float16 sA[2][32 * 64];
    __shared__ __align__(16) _Float16 sB[2][32 * 64];

    const int tid  = threadIdx.x;
    const int lane = tid & 63;
    const int w    = tid >> 6;
    const int wr   = w >> 1, wc = w & 1;
    const int fr   = lane & 15, fg = lane >> 4;

    const int d   = blockIdx.x;
    const int job = (d & 7) * 32 + (d >> 3);   // 256 = 8*32, bijective
    const int bm  = (job & 15) * 32;
    const int bn  = (job >> 4) * 32;

    const int srow = tid >> 3;
    const int cg_  = tid & 7;
    const _Float16* Ap = attnh + (size_t)(bm + srow) * H_ + cg_ * 8;
    const float*    Bp = Wo    + (size_t)(bn + srow) * H_ + cg_ * 8;

    const int sw    = (cg_ ^ (srow & 7)) << 3;
    const int wbase = srow * 64;

    f32x4 acc = {};

    half8  a0 = *(const half8*)Ap;
    float4 b0 = *(const float4*)(Bp + 0), b1 = *(const float4*)(Bp + 4);

    for (int t = 0; t < 16; ++t) {
        const int buf = t & 1;
        half8 hA = a0;
        half8 hB = cvt8(b0, b1);
        if (t < 15) {
            a0 = *(const half8*)(Ap + (t + 1) * 64);
            b0 = *(const float4*)(Bp + (t + 1) * 64);
            b1 = *(const float4*)(Bp + (t + 1) * 64 + 4);
        }
        *(half8*)&sA[buf][wbase + sw] = hA;
        *(half8*)&sB[buf][wbase + sw] = hB;
        barrier_nodrain();

#pragma unroll
        for (int kh = 0; kh < 2; ++kh) {
            const int p = (((kh * 4 + fg) ^ (fr & 7)) << 3);
            half8 af = *(const half8*)&sA[buf][(wr * 16 + fr) * 64 + p];
            half8 bf = *(const half8*)&sB[buf][(wc * 16 + fr) * 64 + p];
            acc = __builtin_amdgcn_mfma_f32_16x16x32_f16(af, bf, acc, 0, 0, 0);
        }
    }

    const int row0 = bm + wr * 16 + fg * 4;
    const int col  = bn + wc * 16 + fr;
    const float badd = bo[col];
#pragma unroll
    for (int r = 0; r < 4; ++r)
        outp[(size_t)(row0 + r) * OUT_ + col] = acc[r] + badd;
}

extern "C" void kernel_launch(void* const* d_in, const int* in_sizes, int n_in,
                              void* d_out, int out_size, void* d_ws, size_t ws_size,
                              hipStream_t stream)
{
    const float* x  = (const float*)d_in[0];
    const float* Wq = (const float*)d_in[1];
    const float* Wk = (const float*)d_in[2];
    const float* Wv = (const float*)d_in[3];
    const float* bv = (const float*)d_in[4];
    const float* Wo = (const float*)d_in[5];
    const float* bo = (const float*)d_in[6];
    float* out = (float*)d_out;

    char* ws = (char*)d_ws;
    _Float16* qkvph = (_Float16*)ws;                 // [2][512][3072] f16 = 6.3 MB
    _Float16* attnh = (_Float16*)(ws + (8 << 20));   // [512][1024] f16 = 1 MB

    qkv_kernel<<<dim3(192), 256, 0, stream>>>(x, Wq, Wk, Wv, qkvph);
    attn_kernel<<<dim3(B_), 256, 0, stream>>>(qkvph, bv, attnh);
    out_kernel<<<dim3(256), 256, 0, stream>>>(attnh, Wo, bo, out);
}

// Round 11
// 35.427 us; speedup vs baseline: 5.2500x; 1.1033x over previous
//
#include <hip/hip_runtime.h>

#define H_    1024
#define B_    512
#define OUT_  512
#define SLAB_ ((size_t)B_ * 3072)

typedef _Float16 half8 __attribute__((ext_vector_type(8)));
typedef _Float16 half4 __attribute__((ext_vector_type(4)));
typedef float    f32x4 __attribute__((ext_vector_type(4)));

__device__ __forceinline__ half8 cvt8(float4 lo, float4 hi) {
    half8 h;
    h[0] = (_Float16)lo.x; h[1] = (_Float16)lo.y; h[2] = (_Float16)lo.z; h[3] = (_Float16)lo.w;
    h[4] = (_Float16)hi.x; h[5] = (_Float16)hi.y; h[6] = (_Float16)hi.z; h[7] = (_Float16)hi.w;
    return h;
}

// Workgroup barrier WITHOUT the vmcnt(0) drain __syncthreads() emits.
__device__ __forceinline__ void barrier_nodrain() {
    asm volatile("s_waitcnt lgkmcnt(0)" ::: "memory");
    __builtin_amdgcn_s_barrier();
}

// ===========================================================================
// qkv, K-split x4: qkvph[kz][B][3072] f16 partials, kz-slab = 256 K-elems.
// 64x64 tiles, BK=64, 4 K-steps, 4 waves (2x2, each 32x32). 1536 blocks
// (~5/CU resident; LDS 32 KB/block) — R6's proven inner loop, deeper split.
// XCD decode: xcd c -> kz = c&3, bn-half = c>>2; owns {8 bm x 24 bn} ->
// per-XCD L2 set = x-quarter 512 KB + 24 W-col-quarters 1.5 MB = 2 MB.
// Swizzle g' = g ^ (row&7) (proven conflict-free R5-R6).
// ===========================================================================
__global__ __launch_bounds__(256) void qkv_kernel(const float* __restrict__ x,
                                                  const float* __restrict__ Wq,
                                                  const float* __restrict__ Wk,
                                                  const float* __restrict__ Wv,
                                                  _Float16* __restrict__ qkvph)
{
    __shared__ __align__(16) _Float16 sA[2][64 * 64];
    __shared__ __align__(16) _Float16 sB[2][64 * 64];

    const int tid  = threadIdx.x;
    const int lane = tid & 63;
    const int w    = tid >> 6;
    const int wr   = w >> 1, wc = w & 1;
    const int fr   = lane & 15, fg = lane >> 4;

    // decode: 1536 = 8 xcd * 192 jobs; job = {bm (fast) x 24 bn}
    const int d    = blockIdx.x;
    const int xcd  = d & 7;
    const int j    = d >> 3;              // 0..191
    const int kz   = xcd & 3;
    const int half = xcd >> 2;
    const int bm   = (j & 7) * 64;
    const int bn   = (half * 24 + (j >> 3)) * 64;   // 0..3008
    const int k0   = kz * 256;

    const int wsel = bn >> 10;
    const float* W = (wsel == 0) ? Wq : (wsel == 1) ? Wk : Wv;
    const int brow = bn & 1023;

    const int srow = tid >> 2;
    const int cq   = tid & 3;
    const float* Ap = x + (size_t)(bm + srow) * H_ + k0 + cq * 16;
    const float* Bp = W + (size_t)(brow + srow) * H_ + k0 + cq * 16;

    const int g0    = (((2 * cq)     ^ (srow & 7)) << 3);
    const int g1    = (((2 * cq + 1) ^ (srow & 7)) << 3);
    const int wbase = srow * 64;

    f32x4 acc[2][2] = {};

    float4 a0 = *(const float4*)(Ap + 0), a1 = *(const float4*)(Ap + 4);
    float4 a2 = *(const float4*)(Ap + 8), a3 = *(const float4*)(Ap + 12);
    float4 b0 = *(const float4*)(Bp + 0), b1 = *(const float4*)(Bp + 4);
    float4 b2 = *(const float4*)(Bp + 8), b3 = *(const float4*)(Bp + 12);

    for (int t = 0; t < 4; ++t) {
        const int buf = t & 1;
        half8 hA0 = cvt8(a0, a1), hA1 = cvt8(a2, a3);
        half8 hB0 = cvt8(b0, b1), hB1 = cvt8(b2, b3);
        if (t < 3) {
            const float* An = Ap + (t + 1) * 64;
            const float* Bn = Bp + (t + 1) * 64;
            a0 = *(const float4*)(An + 0); a1 = *(const float4*)(An + 4);
            a2 = *(const float4*)(An + 8); a3 = *(const float4*)(An + 12);
            b0 = *(const float4*)(Bn + 0); b1 = *(const float4*)(Bn + 4);
            b2 = *(const float4*)(Bn + 8); b3 = *(const float4*)(Bn + 12);
        }
        *(half8*)&sA[buf][wbase + g0] = hA0;
        *(half8*)&sA[buf][wbase + g1] = hA1;
        *(half8*)&sB[buf][wbase + g0] = hB0;
        *(half8*)&sB[buf][wbase + g1] = hB1;
        barrier_nodrain();

#pragma unroll
        for (int kh = 0; kh < 2; ++kh) {
            const int p = (((kh * 4 + fg) ^ (fr & 7)) << 3);
            half8 af[2], bf[2];
#pragma unroll
            for (int mi = 0; mi < 2; ++mi)
                af[mi] = *(const half8*)&sA[buf][(wr * 32 + mi * 16 + fr) * 64 + p];
#pragma unroll
            for (int ni = 0; ni < 2; ++ni)
                bf[ni] = *(const half8*)&sB[buf][(wc * 32 + ni * 16 + fr) * 64 + p];
#pragma unroll
            for (int mi = 0; mi < 2; ++mi)
#pragma unroll
                for (int ni = 0; ni < 2; ++ni)
                    acc[mi][ni] = __builtin_amdgcn_mfma_f32_16x16x32_f16(
                                      af[mi], bf[ni], acc[mi][ni], 0, 0, 0);
        }
        // no trailing barrier: dbuf; same-buffer reuse is 2 iters away,
        // ordered by the next barrier.
    }

    _Float16* Cb = qkvph + (size_t)kz * SLAB_ + (size_t)bm * 3072 + bn;
#pragma unroll
    for (int mi = 0; mi < 2; ++mi) {
        const int r0 = wr * 32 + mi * 16 + fg * 4;
#pragma unroll
        for (int ni = 0; ni < 2; ++ni) {
            const int col = wc * 32 + ni * 16 + fr;
#pragma unroll
            for (int r = 0; r < 4; ++r)
                Cb[(size_t)(r0 + r) * 3072 + col] = (_Float16)acc[mi][ni][r];
        }
    }
}

// ===========================================================================
// attn: per-batch Taylor moments (deg 7) + Horner eval, summing 4 f16
// K-slab partials (+bv on v). s_j = k/32, |c*s| <= ~0.85, rem < 2e-5.
// ===========================================================================
__global__ __launch_bounds__(256) void attn_kernel(const _Float16* __restrict__ qkvph,
                                                   const float* __restrict__ bv,
                                                   _Float16* __restrict__ attnh)
{
    __shared__ float red[4][16];
    __shared__ float sm[16];
    const int b   = blockIdx.x;
    const int tid = threadIdx.x;
    const _Float16* base = qkvph + (size_t)b * 3072;

    float qs[4] = {}, ks[4] = {}, vs[4] = {};
#pragma unroll
    for (int z = 0; z < 4; ++z) {
        const _Float16* pz = base + (size_t)z * SLAB_;
        half4 q4 = ((const half4*)(pz))[tid];
        half4 k4 = ((const half4*)(pz + 1024))[tid];
        half4 v4 = ((const half4*)(pz + 2048))[tid];
#pragma unroll
        for (int e = 0; e < 4; ++e) {
            qs[e] += (float)q4[e];
            ks[e] += (float)k4[e];
            vs[e] += (float)v4[e];
        }
    }
    float4 bv4 = ((const float4*)bv)[tid];
    vs[0] += bv4.x; vs[1] += bv4.y; vs[2] += bv4.z; vs[3] += bv4.w;

    float m[8] = {}, Mv[8] = {};
#pragma unroll
    for (int e = 0; e < 4; ++e) {
        float s = ks[e] * (1.0f / 32.0f);
        float v = vs[e];
        float p = 1.0f;
#pragma unroll
        for (int n = 0; n < 8; ++n) {
            m[n] += p;
            Mv[n] = fmaf(p, v, Mv[n]);
            p *= s;
        }
    }
#pragma unroll
    for (int off = 32; off; off >>= 1)
#pragma unroll
        for (int n = 0; n < 8; ++n) {
            m[n]  += __shfl_xor(m[n],  off, 64);
            Mv[n] += __shfl_xor(Mv[n], off, 64);
        }
    const int wave = tid >> 6;
    if ((tid & 63) == 0) {
#pragma unroll
        for (int n = 0; n < 8; ++n) {
            red[wave][n]     = m[n];
            red[wave][n + 8] = Mv[n];
        }
    }
    __syncthreads();
    if (tid < 16) {
        const float invfact[8] = {1.f, 1.f, 0.5f, 1.f/6.f, 1.f/24.f,
                                  1.f/120.f, 1.f/720.f, 1.f/5040.f};
        sm[tid] = (red[0][tid] + red[1][tid] + red[2][tid] + red[3][tid])
                  * invfact[tid & 7];
    }
    __syncthreads();

    half4 o;
#pragma unroll
    for (int e = 0; e < 4; ++e) {
        float c = qs[e];
        float den = sm[7];
#pragma unroll
        for (int n = 6; n >= 0; --n) den = fmaf(den, c, sm[n]);
        float num = sm[15];
#pragma unroll
        for (int n = 14; n >= 8; --n) num = fmaf(num, c, sm[n]);
        o[e] = (_Float16)(num / den);
    }
    ((half4*)attnh)[b * 256 + tid] = o;
}

// ===========================================================================
// out = attn @ Wo^T + bo. BM=BN=32, 256 blocks (XCD-chunked), BK=64, 16 steps.
// ===========================================================================
__global__ __launch_bounds__(256) void out_kernel(const _Float16* __restrict__ attnh,
                                                  const float* __restrict__ Wo,
                                                  const float* __restrict__ bo,
                                                  float* __restrict__ outp)
{
    __shared__ __align__(16) _Float16 sA[2][32 * 64];
    __shared__ __align__(16) _Float16 sB[2][32 * 64];

    const int tid  = threadIdx.x;
    const int lane = tid & 63;
    const int w    = tid >> 6;
    const int wr   = w >> 1, wc = w & 1;
    const int fr   = lane & 15, fg = lane >> 4;

    const int d   = blockIdx.x;
    const int job = (d & 7) * 32 + (d >> 3);   // 256 = 8*32, bijective
    const int bm  = (job & 15) * 32;
    const int bn  = (job >> 4) * 32;

    const int srow = tid >> 3;
    const int cg_  = tid & 7;
    const _Float16* Ap = attnh + (size_t)(bm + srow) * H_ + cg_ * 8;
    const float*    Bp = Wo    + (size_t)(bn + srow) * H_ + cg_ * 8;

    const int sw    = (cg_ ^ (srow & 7)) << 3;
    const int wbase = srow * 64;

    f32x4 acc = {};

    half8  a0 = *(const half8*)Ap;
    float4 b0 = *(const float4*)(Bp + 0), b1 = *(const float4*)(Bp + 4);

    for (int t = 0; t < 16; ++t) {
        const int buf = t & 1;
        half8 hA = a0;
        half8 hB = cvt8(b0, b1);
        if (t < 15) {
            a0 = *(const half8*)(Ap + (t + 1) * 64);
            b0 = *(const float4*)(Bp + (t + 1) * 64);
            b1 = *(const float4*)(Bp + (t + 1) * 64 + 4);
        }
        *(half8*)&sA[buf][wbase + sw] = hA;
        *(half8*)&sB[buf][wbase + sw] = hB;
        barrier_nodrain();

#pragma unroll
        for (int kh = 0; kh < 2; ++kh) {
            const int p = (((kh * 4 + fg) ^ (fr & 7)) << 3);
            half8 af = *(const half8*)&sA[buf][(wr * 16 + fr) * 64 + p];
            half8 bf = *(const half8*)&sB[buf][(wc * 16 + fr) * 64 + p];
            acc = __builtin_amdgcn_mfma_f32_16x16x32_f16(af, bf, acc, 0, 0, 0);
        }
    }

    const int row0 = bm + wr * 16 + fg * 4;
    const int col  = bn + wc * 16 + fr;
    const float badd = bo[col];
#pragma unroll
    for (int r = 0; r < 4; ++r)
        outp[(size_t)(row0 + r) * OUT_ + col] = acc[r] + badd;
}

extern "C" void kernel_launch(void* const* d_in, const int* in_sizes, int n_in,
                              void* d_out, int out_size, void* d_ws, size_t ws_size,
                              hipStream_t stream)
{
    const float* x  = (const float*)d_in[0];
    const float* Wq = (const float*)d_in[1];
    const float* Wk = (const float*)d_in[2];
    const float* Wv = (const float*)d_in[3];
    const float* bv = (const float*)d_in[4];
    const float* Wo = (const float*)d_in[5];
    const float* bo = (const float*)d_in[6];
    float* out = (float*)d_out;

    char* ws = (char*)d_ws;
    _Float16* qkvph = (_Float16*)ws;                  // [4][512][3072] f16 = 12 MB
    _Float16* attnh = (_Float16*)(ws + (16 << 20));   // [512][1024] f16 = 1 MB

    qkv_kernel<<<dim3(1536), 256, 0, stream>>>(x, Wq, Wk, Wv, qkvph);
    attn_kernel<<<dim3(B_), 256, 0, stream>>>(qkvph, bv, attnh);
    out_kernel<<<dim3(256), 256, 0, stream>>>(attnh, Wo, bo, out);
}

// Round 12
// 30.655 us; speedup vs baseline: 6.0674x; 1.1557x over previous
//
#include <hip/hip_runtime.h>

#define H_    1024
#define B_    512
#define OUT_  512
#define SLAB_ ((size_t)B_ * 3072)   // halves per K-partial slab

typedef _Float16 half8 __attribute__((ext_vector_type(8)));
typedef _Float16 half4 __attribute__((ext_vector_type(4)));
typedef float    f32x4 __attribute__((ext_vector_type(4)));

__device__ __forceinline__ half8 cvt8(float4 lo, float4 hi) {
    half8 h;
    h[0] = (_Float16)lo.x; h[1] = (_Float16)lo.y; h[2] = (_Float16)lo.z; h[3] = (_Float16)lo.w;
    h[4] = (_Float16)hi.x; h[5] = (_Float16)hi.y; h[6] = (_Float16)hi.z; h[7] = (_Float16)hi.w;
    return h;
}

// Workgroup barrier WITHOUT the vmcnt(0) drain __syncthreads() emits.
__device__ __forceinline__ void barrier_nodrain() {
    asm volatile("s_waitcnt lgkmcnt(0)" ::: "memory");
    __builtin_amdgcn_s_barrier();
}

// ===========================================================================
// qkv (R6-proven structure): 64x64 tiles, BK=64, 8 K-steps, K-split x2,
// 4 waves (2x2, each 32x32), 768 blocks, XCD-chunked bm-fastest decode.
// Output: f16 partials qkvph[kz][B][3072] (numerics proven R8/R9/R11).
// ===========================================================================
__global__ __launch_bounds__(256) void qkv_kernel(const float* __restrict__ x,
                                                  const float* __restrict__ Wq,
                                                  const float* __restrict__ Wk,
                                                  const float* __restrict__ Wv,
                                                  _Float16* __restrict__ qkvph)
{
    __shared__ __align__(16) _Float16 sA[2][64 * 64];
    __shared__ __align__(16) _Float16 sB[2][64 * 64];

    const int tid  = threadIdx.x;
    const int lane = tid & 63;
    const int w    = tid >> 6;
    const int wr   = w >> 1, wc = w & 1;
    const int fr   = lane & 15, fg = lane >> 4;

    // XCD-chunked job swizzle (768 = 8 * 96, bijective), bm fastest
    const int d    = blockIdx.x;
    const int job  = (d & 7) * 96 + (d >> 3);
    const int bm   = (job & 7) * 64;
    const int rest = job >> 3;                 // 0..95
    const int kz   = (rest >= 48) ? 1 : 0;
    const int bn   = (rest - kz * 48) * 64;    // 0..3071
    const int k0   = kz * 512;

    const int wsel = bn >> 10;
    const float* W = (wsel == 0) ? Wq : (wsel == 1) ? Wk : Wv;
    const int brow = bn & 1023;

    const int srow = tid >> 2;
    const int cq   = tid & 3;
    const float* Ap = x + (size_t)(bm + srow) * H_ + k0 + cq * 16;
    const float* Bp = W + (size_t)(brow + srow) * H_ + k0 + cq * 16;

    const int g0    = (((2 * cq)     ^ (srow & 7)) << 3);
    const int g1    = (((2 * cq + 1) ^ (srow & 7)) << 3);
    const int wbase = srow * 64;

    f32x4 acc[2][2] = {};

    float4 a0 = *(const float4*)(Ap + 0), a1 = *(const float4*)(Ap + 4);
    float4 a2 = *(const float4*)(Ap + 8), a3 = *(const float4*)(Ap + 12);
    float4 b0 = *(const float4*)(Bp + 0), b1 = *(const float4*)(Bp + 4);
    float4 b2 = *(const float4*)(Bp + 8), b3 = *(const float4*)(Bp + 12);

    for (int t = 0; t < 8; ++t) {
        const int buf = t & 1;
        half8 hA0 = cvt8(a0, a1), hA1 = cvt8(a2, a3);
        half8 hB0 = cvt8(b0, b1), hB1 = cvt8(b2, b3);
        if (t < 7) {
            const float* An = Ap + (t + 1) * 64;
            const float* Bn = Bp + (t + 1) * 64;
            a0 = *(const float4*)(An + 0); a1 = *(const float4*)(An + 4);
            a2 = *(const float4*)(An + 8); a3 = *(const float4*)(An + 12);
            b0 = *(const float4*)(Bn + 0); b1 = *(const float4*)(Bn + 4);
            b2 = *(const float4*)(Bn + 8); b3 = *(const float4*)(Bn + 12);
        }
        *(half8*)&sA[buf][wbase + g0] = hA0;
        *(half8*)&sA[buf][wbase + g1] = hA1;
        *(half8*)&sB[buf][wbase + g0] = hB0;
        *(half8*)&sB[buf][wbase + g1] = hB1;
        barrier_nodrain();

#pragma unroll
        for (int kh = 0; kh < 2; ++kh) {
            const int p = (((kh * 4 + fg) ^ (fr & 7)) << 3);
            half8 af[2], bf[2];
#pragma unroll
            for (int mi = 0; mi < 2; ++mi)
                af[mi] = *(const half8*)&sA[buf][(wr * 32 + mi * 16 + fr) * 64 + p];
#pragma unroll
            for (int ni = 0; ni < 2; ++ni)
                bf[ni] = *(const half8*)&sB[buf][(wc * 32 + ni * 16 + fr) * 64 + p];
#pragma unroll
            for (int mi = 0; mi < 2; ++mi)
#pragma unroll
                for (int ni = 0; ni < 2; ++ni)
                    acc[mi][ni] = __builtin_amdgcn_mfma_f32_16x16x32_f16(
                                      af[mi], bf[ni], acc[mi][ni], 0, 0, 0);
        }
    }

    _Float16* Cb = qkvph + (size_t)kz * SLAB_ + (size_t)bm * 3072 + bn;
#pragma unroll
    for (int mi = 0; mi < 2; ++mi) {
        const int r0 = wr * 32 + mi * 16 + fg * 4;
#pragma unroll
        for (int ni = 0; ni < 2; ++ni) {
            const int col = wc * 32 + ni * 16 + fr;
#pragma unroll
            for (int r = 0; r < 4; ++r)
                Cb[(size_t)(r0 + r) * 3072 + col] = (_Float16)acc[mi][ni][r];
        }
    }
}

// ===========================================================================
// attn: Taylor moments (deg 7) + Horner eval from 2 f16 K-partials (+bv).
// ALSO initializes out-row b to bo (so out_kernel can pure-atomicAdd).
// ===========================================================================
__global__ __launch_bounds__(256) void attn_kernel(const _Float16* __restrict__ qkvph,
                                                   const float* __restrict__ bv,
                                                   const float* __restrict__ bo,
                                                   _Float16* __restrict__ attnh,
                                                   float* __restrict__ outp)
{
    __shared__ float red[4][16];
    __shared__ float sm[16];
    const int b   = blockIdx.x;
    const int tid = threadIdx.x;
    const _Float16* p0 = qkvph + (size_t)b * 3072;
    const _Float16* p1 = p0 + SLAB_;

    // init out row b = bo (128 float4 writes by threads 0..127)
    if (tid < 128)
        ((float4*)(outp + (size_t)b * OUT_))[tid] = ((const float4*)bo)[tid];

    half4 ka = ((const half4*)(p0 + 1024))[tid];
    half4 kb = ((const half4*)(p1 + 1024))[tid];
    half4 va = ((const half4*)(p0 + 2048))[tid];
    half4 vb = ((const half4*)(p1 + 2048))[tid];
    float4 bv4 = ((const float4*)bv)[tid];

    const float ks[4] = {(float)ka[0] + (float)kb[0], (float)ka[1] + (float)kb[1],
                         (float)ka[2] + (float)kb[2], (float)ka[3] + (float)kb[3]};
    const float vs[4] = {(float)va[0] + (float)vb[0] + bv4.x,
                         (float)va[1] + (float)vb[1] + bv4.y,
                         (float)va[2] + (float)vb[2] + bv4.z,
                         (float)va[3] + (float)vb[3] + bv4.w};

    float m[8] = {}, Mv[8] = {};
#pragma unroll
    for (int e = 0; e < 4; ++e) {
        float s = ks[e] * (1.0f / 32.0f);
        float v = vs[e];
        float p = 1.0f;
#pragma unroll
        for (int n = 0; n < 8; ++n) {
            m[n] += p;
            Mv[n] = fmaf(p, v, Mv[n]);
            p *= s;
        }
    }
#pragma unroll
    for (int off = 32; off; off >>= 1)
#pragma unroll
        for (int n = 0; n < 8; ++n) {
            m[n]  += __shfl_xor(m[n],  off, 64);
            Mv[n] += __shfl_xor(Mv[n], off, 64);
        }
    const int wave = tid >> 6;
    if ((tid & 63) == 0) {
#pragma unroll
        for (int n = 0; n < 8; ++n) {
            red[wave][n]     = m[n];
            red[wave][n + 8] = Mv[n];
        }
    }
    __syncthreads();
    if (tid < 16) {
        const float invfact[8] = {1.f, 1.f, 0.5f, 1.f/6.f, 1.f/24.f,
                                  1.f/120.f, 1.f/720.f, 1.f/5040.f};
        sm[tid] = (red[0][tid] + red[1][tid] + red[2][tid] + red[3][tid])
                  * invfact[tid & 7];
    }
    __syncthreads();

    half4 qa = ((const half4*)p0)[tid];
    half4 qb = ((const half4*)p1)[tid];
    half4 o;
#pragma unroll
    for (int e = 0; e < 4; ++e) {
        float c = (float)qa[e] + (float)qb[e];
        float den = sm[7];
#pragma unroll
        for (int n = 6; n >= 0; --n) den = fmaf(den, c, sm[n]);
        float num = sm[15];
#pragma unroll
        for (int n = 14; n >= 8; --n) num = fmaf(num, c, sm[n]);
        o[e] = (_Float16)(num / den);
    }
    ((half4*)attnh)[b * 256 + tid] = o;
}

// ===========================================================================
// out += attn @ Wo^T (bias pre-initialized by attn_kernel). BM=BN=32,
// K-split x2 -> 512 blocks (2/CU), 8 steps each, f32 atomicAdd epilogue
// (exactly 2 commutative adds per element -> deterministic).
// Decode: xcd c owns kz = c&1, bn pair (c>>1), all 16 bm.
// ===========================================================================
__global__ __launch_bounds__(256) void out_kernel(const _Float16* __restrict__ attnh,
                                                  const float* __restrict__ Wo,
                                                  float* __restrict__ outp)
{
    __shared__ __align__(16) _Float16 sA[2][32 * 64];
    __shared__ __align__(16) _Float16 sB[2][32 * 64];

    const int tid  = threadIdx.x;
    const int lane = tid & 63;
    const int w    = tid >> 6;
    const int wr   = w >> 1, wc = w & 1;
    const int fr   = lane & 15, fg = lane >> 4;

    // 512 = 8 xcd * 64 jobs; job = {16 bm (fast) x 4 bn}; kz = xcd&1
    const int d   = blockIdx.x;
    const int xcd = d & 7;
    const int j   = d >> 3;                  // 0..63
    const int kz  = xcd & 1;
    const int bm  = (j & 15) * 32;
    const int bn  = ((xcd >> 1) * 4 + (j >> 4)) * 32;   // 0..480
    const int k0  = kz * 512;

    const int srow = tid >> 3;
    const int cg_  = tid & 7;
    const _Float16* Ap = attnh + (size_t)(bm + srow) * H_ + k0 + cg_ * 8;
    const float*    Bp = Wo    + (size_t)(bn + srow) * H_ + k0 + cg_ * 8;

    const int sw    = (cg_ ^ (srow & 7)) << 3;
    const int wbase = srow * 64;

    f32x4 acc = {};

    half8  a0 = *(const half8*)Ap;
    float4 b0 = *(const float4*)(Bp + 0), b1 = *(const float4*)(Bp + 4);

    for (int t = 0; t < 8; ++t) {
        const int buf = t & 1;
        half8 hA = a0;
        half8 hB = cvt8(b0, b1);
        if (t < 7) {
            a0 = *(const half8*)(Ap + (t + 1) * 64);
            b0 = *(const float4*)(Bp + (t + 1) * 64);
            b1 = *(const float4*)(Bp + (t + 1) * 64 + 4);
        }
        *(half8*)&sA[buf][wbase + sw] = hA;
        *(half8*)&sB[buf][wbase + sw] = hB;
        barrier_nodrain();

#pragma unroll
        for (int kh = 0; kh < 2; ++kh) {
            const int p = (((kh * 4 + fg) ^ (fr & 7)) << 3);
            half8 af = *(const half8*)&sA[buf][(wr * 16 + fr) * 64 + p];
            half8 bf = *(const half8*)&sB[buf][(wc * 16 + fr) * 64 + p];
            acc = __builtin_amdgcn_mfma_f32_16x16x32_f16(af, bf, acc, 0, 0, 0);
        }
    }

    const int row0 = bm + wr * 16 + fg * 4;
    const int col  = bn + wc * 16 + fr;
#pragma unroll
    for (int r = 0; r < 4; ++r)
        atomicAdd(&outp[(size_t)(row0 + r) * OUT_ + col], acc[r]);
}

extern "C" void kernel_launch(void* const* d_in, const int* in_sizes, int n_in,
                              void* d_out, int out_size, void* d_ws, size_t ws_size,
                              hipStream_t stream)
{
    const float* x  = (const float*)d_in[0];
    const float* Wq = (const float*)d_in[1];
    const float* Wk = (const float*)d_in[2];
    const float* Wv = (const float*)d_in[3];
    const float* bv = (const float*)d_in[4];
    const float* Wo = (const float*)d_in[5];
    const float* bo = (const float*)d_in[6];
    float* out = (float*)d_out;

    char* ws = (char*)d_ws;
    _Float16* qkvph = (_Float16*)ws;                 // [2][512][3072] f16 = 6.3 MB
    _Float16* attnh = (_Float16*)(ws + (8 << 20));   // [512][1024] f16 = 1 MB

    qkv_kernel<<<dim3(768), 256, 0, stream>>>(x, Wq, Wk, Wv, qkvph);
    attn_kernel<<<dim3(B_), 256, 0, stream>>>(qkvph, bv, bo, attnh, out);
    out_kernel<<<dim3(512), 256, 0, stream>>>(attnh, Wo, out);
}